// Round 7
// baseline (133.498 us; speedup 1.0000x reference)
//
#include <hip/hip_runtime.h>
#include <hip/hip_bf16.h>

#define NFEA 128
#define NCLS 5
#define LN_EPS 1e-5f
#define CHUNK 256    // atoms per chunk
#define NBLK 2048    // persistent blocks: 256 CU x 8 blocks/CU

typedef float f32x4 __attribute__((ext_vector_type(4)));

// LN -> softplus -> head, register-f32x4 layout (validated R5/R6):
// lane holds features [4*fc, 4*fc+4); both 32-lane halves redundant.
__device__ __forceinline__ void finalize_vec(
    int lane, int fc, int c, f32x4 sum, float inv_len,
    const float* __restrict__ lnw, const float* __restrict__ lnb,
    const float* __restrict__ outw, const float* __restrict__ outb,
    float* __restrict__ out_cls, float* __restrict__ out_act)
{
    f32x4 p;
    p[0] = sum[0] * inv_len; p[1] = sum[1] * inv_len;
    p[2] = sum[2] * inv_len; p[3] = sum[3] * inv_len;

    float t = p[0] + p[1] + p[2] + p[3];
    #pragma unroll
    for (int off = 16; off; off >>= 1) t += __shfl_xor(t, off);
    const float mu = t * (1.f / NFEA);

    f32x4 d;
    d[0] = p[0] - mu; d[1] = p[1] - mu; d[2] = p[2] - mu; d[3] = p[3] - mu;
    float v = d[0]*d[0] + d[1]*d[1] + d[2]*d[2] + d[3]*d[3];
    #pragma unroll
    for (int off = 16; off; off >>= 1) v += __shfl_xor(v, off);
    const float rstd = rsqrtf(v * (1.f / NFEA) + LN_EPS);

    const f32x4 w4 = ((const f32x4*)lnw)[fc];
    const f32x4 b4 = ((const f32x4*)lnb)[fc];
    f32x4 act;
    #pragma unroll
    for (int j = 0; j < 4; ++j) {
        const float x = d[j] * rstd * w4[j] + b4[j];
        act[j] = (x > 0.f) ? x + log1pf(expf(-x)) : log1pf(expf(x));
    }
    if (lane < 32) ((f32x4*)out_act)[(size_t)c * 32 + fc] = act;

    #pragma unroll
    for (int k = 0; k < NCLS; ++k) {
        const f32x4 wk = ((const f32x4*)outw)[k * 32 + fc];
        float pk = act[0]*wk[0] + act[1]*wk[1] + act[2]*wk[2] + act[3]*wk[3];
        #pragma unroll
        for (int off = 16; off; off >>= 1) pk += __shfl_xor(pk, off);
        if (lane == k) out_cls[(size_t)c * NCLS + k] = pk + outb[k];
    }
}

// Prep: zero seg_sum + chunk -> first-segment map.
__global__ __launch_bounds__(256) void prep_kernel(
    const int2* __restrict__ idx,
    int*  __restrict__ seg_of_chunk,    // [n_atoms/CHUNK]
    float* __restrict__ seg_sum,        // [n_crys][128]
    int n_crys)
{
    const int t    = blockIdx.x * 256 + threadIdx.x;
    const int nthr = gridDim.x * 256;

    f32x4* z = (f32x4*)seg_sum;
    const int nz = n_crys * NFEA / 4;
    for (int i = t; i < nz; i += nthr) z[i] = (f32x4){0.f, 0.f, 0.f, 0.f};

    if (t < n_crys) {
        const int2 se = idx[t];
        int j = (se.x + CHUNK - 1) / CHUNK;
        for (; j * CHUNK < se.y; ++j) seg_of_chunk[j] = t;
    }
}

// Main: persistent blocks grid-stride over 256-atom chunks. Per run:
// R2's 2-deep stride-8 loader, double-buffered LDS reduce (ONE barrier/run),
// atomicAdd partials. Waves 2-3 start next run's loads during the reduce.
__global__ __launch_bounds__(256) void seg_sum_kernel(
    const float* __restrict__ fea,       // [N_ATOMS][128]
    const int2*  __restrict__ idx,
    const int*   __restrict__ seg_of_chunk,
    float* __restrict__ seg_sum,
    int nchunk)
{
    const int tid = threadIdx.x;
    const int fc  = tid & 31;
    const int al  = tid >> 5;

    const f32x4* __restrict__ fea4 = (const f32x4*)fea;
    __shared__ f32x4 red4[2][8][32];    // double-buffered: 1 barrier per run
    int p = 0;

    for (int j = blockIdx.x; j < nchunk; j += gridDim.x) {
        const int c0 = j * CHUNK;
        const int c1 = c0 + CHUNK;
        int s  = seg_of_chunk[j];
        int rs = c0;

        while (rs < c1) {
            const int re = min(idx[s].y, c1);

            f32x4 acc0 = {0.f,0.f,0.f,0.f};
            f32x4 acc1 = {0.f,0.f,0.f,0.f};

            int a = rs + al;
            if (a + 8 < re) {
                f32x4 v0 = fea4[(size_t)a       * 32 + fc];
                f32x4 v1 = fea4[(size_t)(a + 8) * 32 + fc];
                a += 16;
                for (; a + 8 < re; a += 16) {
                    f32x4 n0 = fea4[(size_t)a       * 32 + fc];
                    f32x4 n1 = fea4[(size_t)(a + 8) * 32 + fc];
                    acc0 += v0; acc1 += v1;
                    v0 = n0; v1 = n1;
                }
                acc0 += v0; acc1 += v1;
            }
            for (; a < re; a += 8)
                acc0 += fea4[(size_t)a * 32 + fc];

            red4[p][al][fc] = acc0 + acc1;
            __syncthreads();
            if (tid < NFEA) {
                const float* redf = (const float*)red4[p];   // [8][128]
                float ssum = 0.f;
                #pragma unroll
                for (int g = 0; g < 8; ++g) ssum += redf[g * NFEA + tid];
                atomicAdd(&seg_sum[(size_t)s * NFEA + tid], ssum);
            }
            // no second barrier: next run writes red4[p^1]; red4[p] is only
            // rewritten after the NEXT barrier, by which time reducers passed it.
            p ^= 1;
            rs = re; ++s;
        }
    }
}

// Finalize: 4 crystals per 256-thread block, one wave each (validated R6).
__global__ __launch_bounds__(256) void finalize_kernel(
    const float* __restrict__ seg_sum,
    const int2*  __restrict__ idx,
    const float* __restrict__ lnw, const float* __restrict__ lnb,
    const float* __restrict__ outw, const float* __restrict__ outb,
    float* __restrict__ out_cls, float* __restrict__ out_act,
    int n_crys)
{
    const int c    = (blockIdx.x * 256 + threadIdx.x) >> 6;
    const int lane = threadIdx.x & 63;
    if (c >= n_crys) return;
    const int2 se = idx[c];
    const int fc = lane & 31;
    const f32x4 sum = ((const f32x4*)seg_sum)[(size_t)c * 32 + fc];
    finalize_vec(lane, fc, c, sum, 1.f / (float)(se.y - se.x),
                 lnw, lnb, outw, outb, out_cls, out_act);
}

extern "C" void kernel_launch(void* const* d_in, const int* in_sizes, int n_in,
                              void* d_out, int out_size, void* d_ws, size_t ws_size,
                              hipStream_t stream) {
    const float* fea  = (const float*)d_in[0];   // [1048576][128] f32
    const int2*  idx  = (const int2*)d_in[1];    // [8192][2] i32
    const float* lnw  = (const float*)d_in[2];
    const float* lnb  = (const float*)d_in[3];
    const float* outw = (const float*)d_in[4];
    const float* outb = (const float*)d_in[5];

    const int n_crys  = in_sizes[1] / 2;         // 8192
    const int n_atoms = in_sizes[0] / NFEA;      // 1048576
    const int nchunk  = n_atoms / CHUNK;         // 4096

    float* seg_sum      = (float*)d_ws;                                   // 4 MB
    int*   seg_of_chunk = (int*)((char*)d_ws + (size_t)n_crys * NFEA * sizeof(float));

    float* out_cls = (float*)d_out;                          // 8192*5
    float* out_act = (float*)d_out + (size_t)n_crys * NCLS;  // 8192*128

    prep_kernel<<<256, 256, 0, stream>>>(idx, seg_of_chunk, seg_sum, n_crys);
    seg_sum_kernel<<<NBLK, 256, 0, stream>>>(fea, idx, seg_of_chunk, seg_sum, nchunk);
    finalize_kernel<<<(n_crys + 3) / 4, 256, 0, stream>>>(
        seg_sum, idx, lnw, lnb, outw, outb, out_cls, out_act, n_crys);
}

// Round 8
// 129.727 us; speedup vs baseline: 1.0291x; 1.0291x over previous
//
#include <hip/hip_runtime.h>
#include <hip/hip_bf16.h>

#define NFEA 128
#define NCLS 5
#define LN_EPS 1e-5f
#define CHUNK 128   // atoms per block-owned chunk (R2's measured-best geometry)

typedef float f32x4 __attribute__((ext_vector_type(4)));

// LN -> softplus -> head, register-f32x4 layout (validated R5/R6):
// lane holds features [4*fc, 4*fc+4); both 32-lane halves redundant.
__device__ __forceinline__ void finalize_vec(
    int lane, int fc, int c, f32x4 sum, float inv_len,
    const float* __restrict__ lnw, const float* __restrict__ lnb,
    const float* __restrict__ outw, const float* __restrict__ outb,
    float* __restrict__ out_cls, float* __restrict__ out_act)
{
    f32x4 p;
    p[0] = sum[0] * inv_len; p[1] = sum[1] * inv_len;
    p[2] = sum[2] * inv_len; p[3] = sum[3] * inv_len;

    float t = p[0] + p[1] + p[2] + p[3];
    #pragma unroll
    for (int off = 16; off; off >>= 1) t += __shfl_xor(t, off);
    const float mu = t * (1.f / NFEA);

    f32x4 d;
    d[0] = p[0] - mu; d[1] = p[1] - mu; d[2] = p[2] - mu; d[3] = p[3] - mu;
    float v = d[0]*d[0] + d[1]*d[1] + d[2]*d[2] + d[3]*d[3];
    #pragma unroll
    for (int off = 16; off; off >>= 1) v += __shfl_xor(v, off);
    const float rstd = rsqrtf(v * (1.f / NFEA) + LN_EPS);

    const f32x4 w4 = ((const f32x4*)lnw)[fc];
    const f32x4 b4 = ((const f32x4*)lnb)[fc];
    f32x4 act;
    #pragma unroll
    for (int j = 0; j < 4; ++j) {
        const float x = d[j] * rstd * w4[j] + b4[j];
        act[j] = (x > 0.f) ? x + log1pf(expf(-x)) : log1pf(expf(x));
    }
    if (lane < 32) ((f32x4*)out_act)[(size_t)c * 32 + fc] = act;

    #pragma unroll
    for (int k = 0; k < NCLS; ++k) {
        const f32x4 wk = ((const f32x4*)outw)[k * 32 + fc];
        float pk = act[0]*wk[0] + act[1]*wk[1] + act[2]*wk[2] + act[3]*wk[3];
        #pragma unroll
        for (int off = 16; off; off >>= 1) pk += __shfl_xor(pk, off);
        if (lane == k) out_cls[(size_t)c * NCLS + k] = pk + outb[k];
    }
}

// Prep: zero seg_sum (replaces the memset launch) + chunk -> first-segment map
// (replaces main kernel's per-block binary search).
__global__ __launch_bounds__(256) void prep_kernel(
    const int2* __restrict__ idx,
    int*  __restrict__ seg_of_chunk,    // [n_atoms/CHUNK]
    float* __restrict__ seg_sum,        // [n_crys][128]
    int n_crys)
{
    const int t    = blockIdx.x * 256 + threadIdx.x;
    const int nthr = gridDim.x * 256;

    f32x4* z = (f32x4*)seg_sum;
    const int nz = n_crys * NFEA / 4;
    for (int i = t; i < nz; i += nthr) z[i] = (f32x4){0.f, 0.f, 0.f, 0.f};

    if (t < n_crys) {
        const int2 se = idx[t];
        int j = (se.x + CHUNK - 1) / CHUNK;
        for (; j * CHUNK < se.y; ++j) seg_of_chunk[j] = t;
    }
}

// Main: R2's exact measured-best structure. Block owns a 128-atom chunk,
// 8 atom-lanes x 32 f32x4 cols, 2-deep stride-8 software pipeline,
// LDS 8->1 reduce, atomicAdd partials per run, 2 barriers per run.
__global__ __launch_bounds__(256) void seg_sum_kernel(
    const float* __restrict__ fea,       // [N_ATOMS][128]
    const int2*  __restrict__ idx,
    const int*   __restrict__ seg_of_chunk,
    float* __restrict__ seg_sum)
{
    const int c0  = blockIdx.x * CHUNK;
    const int c1  = c0 + CHUNK;
    const int tid = threadIdx.x;
    const int fc  = tid & 31;
    const int al  = tid >> 5;

    int s = seg_of_chunk[blockIdx.x];
    const f32x4* __restrict__ fea4 = (const f32x4*)fea;
    __shared__ f32x4 red4[8][32];

    int rs = c0;
    while (rs < c1) {
        const int re = min(idx[s].y, c1);

        f32x4 acc0 = {0.f,0.f,0.f,0.f};
        f32x4 acc1 = {0.f,0.f,0.f,0.f};

        int a = rs + al;
        if (a + 8 < re) {
            f32x4 v0 = fea4[(size_t)a       * 32 + fc];
            f32x4 v1 = fea4[(size_t)(a + 8) * 32 + fc];
            a += 16;
            for (; a + 8 < re; a += 16) {
                f32x4 n0 = fea4[(size_t)a       * 32 + fc];
                f32x4 n1 = fea4[(size_t)(a + 8) * 32 + fc];
                acc0 += v0; acc1 += v1;
                v0 = n0; v1 = n1;
            }
            acc0 += v0; acc1 += v1;
        }
        for (; a < re; a += 8)
            acc0 += fea4[(size_t)a * 32 + fc];

        red4[al][fc] = acc0 + acc1;
        __syncthreads();
        if (tid < NFEA) {
            const float* redf = (const float*)red4;   // [8][128]
            float ssum = 0.f;
            #pragma unroll
            for (int g = 0; g < 8; ++g) ssum += redf[g * NFEA + tid];
            atomicAdd(&seg_sum[(size_t)s * NFEA + tid], ssum);
        }
        __syncthreads();
        rs = re; ++s;
    }
}

// Finalize: 4 crystals per 256-thread block, one wave each (validated R6).
__global__ __launch_bounds__(256) void finalize_kernel(
    const float* __restrict__ seg_sum,
    const int2*  __restrict__ idx,
    const float* __restrict__ lnw, const float* __restrict__ lnb,
    const float* __restrict__ outw, const float* __restrict__ outb,
    float* __restrict__ out_cls, float* __restrict__ out_act,
    int n_crys)
{
    const int c    = (blockIdx.x * 256 + threadIdx.x) >> 6;
    const int lane = threadIdx.x & 63;
    if (c >= n_crys) return;
    const int2 se = idx[c];
    const int fc = lane & 31;
    const f32x4 sum = ((const f32x4*)seg_sum)[(size_t)c * 32 + fc];
    finalize_vec(lane, fc, c, sum, 1.f / (float)(se.y - se.x),
                 lnw, lnb, outw, outb, out_cls, out_act);
}

extern "C" void kernel_launch(void* const* d_in, const int* in_sizes, int n_in,
                              void* d_out, int out_size, void* d_ws, size_t ws_size,
                              hipStream_t stream) {
    const float* fea  = (const float*)d_in[0];   // [1048576][128] f32
    const int2*  idx  = (const int2*)d_in[1];    // [8192][2] i32
    const float* lnw  = (const float*)d_in[2];
    const float* lnb  = (const float*)d_in[3];
    const float* outw = (const float*)d_in[4];
    const float* outb = (const float*)d_in[5];

    const int n_crys  = in_sizes[1] / 2;         // 8192
    const int n_atoms = in_sizes[0] / NFEA;      // 1048576
    const int nchunk  = n_atoms / CHUNK;         // 8192

    float* seg_sum      = (float*)d_ws;                                   // 4 MB
    int*   seg_of_chunk = (int*)((char*)d_ws + (size_t)n_crys * NFEA * sizeof(float));

    float* out_cls = (float*)d_out;                          // 8192*5
    float* out_act = (float*)d_out + (size_t)n_crys * NCLS;  // 8192*128

    prep_kernel<<<256, 256, 0, stream>>>(idx, seg_of_chunk, seg_sum, n_crys);
    seg_sum_kernel<<<nchunk, 256, 0, stream>>>(fea, idx, seg_of_chunk, seg_sum);
    finalize_kernel<<<(n_crys + 3) / 4, 256, 0, stream>>>(
        seg_sum, idx, lnw, lnb, outw, outb, out_cls, out_act, n_crys);
}

// Round 9
// 124.076 us; speedup vs baseline: 1.0759x; 1.0455x over previous
//
#include <hip/hip_runtime.h>
#include <hip/hip_bf16.h>

#define NFEA 128
#define NCLS 5
#define LN_EPS 1e-5f
#define CHUNK 128   // atoms per block in the partial-sum kernel

// Kernel A: perfectly load-balanced segment partial sums.
// Each block owns a fixed slab of CHUNK atoms, splits it at segment
// boundaries (avg ~2 runs/slab), and atomicAdds 128-float partials.
// 256 threads = 8 atom-lanes x 32 float4 feature-chunks.
__global__ __launch_bounds__(256) void seg_partial_kernel(
    const float* __restrict__ fea,      // [N_ATOMS][128]
    const int2*  __restrict__ idx,      // [N_CRYS] (start, end)
    float* __restrict__ seg_sum,        // [N_CRYS][128] (pre-zeroed ws)
    int n_crys)
{
    const int a0 = blockIdx.x * CHUNK;
    const int a1 = a0 + CHUNK;          // N_ATOMS is a multiple of CHUNK

    // largest s with idx[s].x <= a0 (starts are sorted, cover [0, N_ATOMS))
    int lo = 0, hi = n_crys - 1;
    while (lo < hi) {
        int mid = (lo + hi + 1) >> 1;
        if (idx[mid].x <= a0) lo = mid; else hi = mid - 1;
    }
    int s = lo;

    const int tid = threadIdx.x;
    const int fc  = tid & 31;   // float4 chunk within the 128-feature row
    const int al  = tid >> 5;   // atom lane 0..7

    const float4* __restrict__ fea4 = (const float4*)fea;
    __shared__ float4 red4[8][32];

    int rs = a0;
    while (rs < a1) {                       // uniform across the block
        const int re = min(idx[s].y, a1);   // run = this segment ∩ slab

        // 2-wide unrolled cooperative sum of [rs, re)
        float4 acc0 = make_float4(0.f, 0.f, 0.f, 0.f);
        float4 acc1 = make_float4(0.f, 0.f, 0.f, 0.f);
        int a = rs + al;
        for (; a + 8 < re; a += 16) {
            float4 v0 = fea4[(size_t)a * 32 + fc];
            float4 v1 = fea4[(size_t)(a + 8) * 32 + fc];
            acc0.x += v0.x; acc0.y += v0.y; acc0.z += v0.z; acc0.w += v0.w;
            acc1.x += v1.x; acc1.y += v1.y; acc1.z += v1.z; acc1.w += v1.w;
        }
        if (a < re) {
            float4 v = fea4[(size_t)a * 32 + fc];
            acc0.x += v.x; acc0.y += v.y; acc0.z += v.z; acc0.w += v.w;
        }
        acc0.x += acc1.x; acc0.y += acc1.y; acc0.z += acc1.z; acc0.w += acc1.w;

        red4[al][fc] = acc0;
        __syncthreads();
        if (tid < NFEA) {
            const float* redf = (const float*)red4;   // [8][128]
            float ssum = 0.f;
            #pragma unroll
            for (int g = 0; g < 8; ++g) ssum += redf[g * NFEA + tid];
            atomicAdd(&seg_sum[(size_t)s * NFEA + tid], ssum);
        }
        __syncthreads();
        rs = re; ++s;
    }
}

// Kernel B: one 64-lane wave per crystal: mean -> LN -> softplus -> head.
__global__ __launch_bounds__(64) void finalize_kernel(
    const float* __restrict__ seg_sum,  // [N_CRYS][128]
    const int2*  __restrict__ idx,
    const float* __restrict__ lnw,
    const float* __restrict__ lnb,
    const float* __restrict__ outw,     // [5][128]
    const float* __restrict__ outb,     // [5]
    float* __restrict__ out_cls,        // [N_CRYS][5]
    float* __restrict__ out_act)        // [N_CRYS][128]
{
    const int c   = blockIdx.x;
    const int tid = threadIdx.x;
    const int2 se = idx[c];
    const float inv_len = 1.f / (float)(se.y - se.x);

    float p0 = seg_sum[(size_t)c * NFEA + tid]      * inv_len;
    float p1 = seg_sum[(size_t)c * NFEA + tid + 64] * inv_len;

    float t = p0 + p1;
    #pragma unroll
    for (int off = 32; off; off >>= 1) t += __shfl_xor(t, off);
    const float mu = t * (1.f / NFEA);

    const float d0 = p0 - mu, d1 = p1 - mu;
    float v = d0 * d0 + d1 * d1;
    #pragma unroll
    for (int off = 32; off; off >>= 1) v += __shfl_xor(v, off);
    const float rstd = rsqrtf(v * (1.f / NFEA) + LN_EPS);

    const float x0 = d0 * rstd * lnw[tid]      + lnb[tid];
    const float x1 = d1 * rstd * lnw[tid + 64] + lnb[tid + 64];
    const float a0 = (x0 > 0.f) ? x0 + log1pf(expf(-x0)) : log1pf(expf(x0));
    const float a1 = (x1 > 0.f) ? x1 + log1pf(expf(-x1)) : log1pf(expf(x1));

    out_act[(size_t)c * NFEA + tid]      = a0;
    out_act[(size_t)c * NFEA + tid + 64] = a1;

    #pragma unroll
    for (int k = 0; k < NCLS; ++k) {
        float p = a0 * outw[k * NFEA + tid] + a1 * outw[k * NFEA + tid + 64];
        #pragma unroll
        for (int off = 32; off; off >>= 1) p += __shfl_xor(p, off);
        if (tid == k) out_cls[(size_t)c * NCLS + k] = p + outb[k];
    }
}

extern "C" void kernel_launch(void* const* d_in, const int* in_sizes, int n_in,
                              void* d_out, int out_size, void* d_ws, size_t ws_size,
                              hipStream_t stream) {
    const float* fea  = (const float*)d_in[0];   // [1048576][128] f32
    const int2*  idx  = (const int2*)d_in[1];    // [8192][2] i32
    const float* lnw  = (const float*)d_in[2];
    const float* lnb  = (const float*)d_in[3];
    const float* outw = (const float*)d_in[4];
    const float* outb = (const float*)d_in[5];

    const int n_crys  = in_sizes[1] / 2;         // 8192
    const int n_atoms = in_sizes[0] / NFEA;      // 1048576

    float* seg_sum = (float*)d_ws;               // [n_crys][128] partials
    float* out_cls = (float*)d_out;                          // 8192*5
    float* out_act = (float*)d_out + (size_t)n_crys * NCLS;  // 8192*128

    hipMemsetAsync(seg_sum, 0, (size_t)n_crys * NFEA * sizeof(float), stream);

    seg_partial_kernel<<<n_atoms / CHUNK, 256, 0, stream>>>(fea, idx, seg_sum, n_crys);
    finalize_kernel<<<n_crys, 64, 0, stream>>>(seg_sum, idx, lnw, lnb, outw, outb,
                                               out_cls, out_act);
}